// Round 2
// baseline (5454.759 us; speedup 1.0000x reference)
//
#include <hip/hip_runtime.h>
#include <cstdint>
#include <cstddef>

typedef unsigned short ushort_t;
typedef __attribute__((ext_vector_type(8))) short frag16;
typedef __attribute__((ext_vector_type(8))) unsigned short u16x8;
typedef __attribute__((ext_vector_type(4))) float f32x4;

#define SEQ   512
#define INF   512
#define HID   1024
#define OUTF  512
#define GROUPS 8
#define BPG    32   // blocks per group
#define NB     8    // batches per group
#define RPB    32   // W_hh rows per block

__device__ __forceinline__ float b2f(ushort_t u) {
    union { unsigned int i; float f; } v; v.i = ((unsigned int)u) << 16; return v.f;
}
__device__ __forceinline__ ushort_t f2b(float f) {  // RNE fp32->bf16
    unsigned int u = __float_as_uint(f);
    unsigned int r = (u + 0x7fffu + ((u >> 16) & 1u)) >> 16;
    return (ushort_t)r;
}

// convert 8 contiguous fp32 -> bf16 hi (+ optional lo residual)
__device__ __forceinline__ void cvt8_hilo(const float* __restrict__ src, u16x8* hi, u16x8* lo) {
    const float4 x0 = *(const float4*)src;
    const float4 x1 = *(const float4*)(src + 4);
    float xs[8] = {x0.x,x0.y,x0.z,x0.w,x1.x,x1.y,x1.z,x1.w};
    u16x8 h, l;
#pragma unroll
    for (int j = 0; j < 8; ++j) {
        const ushort_t hb = f2b(xs[j]);
        h[j] = hb;
        l[j] = f2b(xs[j] - b2f(hb));
    }
    *hi = h; if (lo) *lo = l;
}
__device__ __forceinline__ u16x8 cvt8_hi(const float* __restrict__ src) {
    const float4 x0 = *(const float4*)src;
    const float4 x1 = *(const float4*)(src + 4);
    float xs[8] = {x0.x,x0.y,x0.z,x0.w,x1.x,x1.y,x1.z,x1.w};
    u16x8 h;
#pragma unroll
    for (int j = 0; j < 8; ++j) h[j] = f2b(xs[j]);
    return h;
}

// ---------------- Phase 1: XP[m][n] = sum_k X[m,k]*Wih[n,k] + bih[n] + bhh[n] ----
// A (=X) is hi/lo split for accuracy; B (=Wih) single bf16.
__global__ __launch_bounds__(256, 2)
void xproj_kernel(const float* __restrict__ X, const float* __restrict__ Wih,
                  const float* __restrict__ bih, const float* __restrict__ bhh,
                  float* __restrict__ XP)
{
    __shared__ ushort_t Ah[128][40];   // pad 32->40 (stride 20 words) for bank spread
    __shared__ ushort_t Al[128][40];
    __shared__ ushort_t Bs[128][40];
    const int tid = (int)threadIdx.x;
    const int m0 = (int)blockIdx.x * 128;
    const int n0 = (int)blockIdx.y * 128;
    const int w  = tid >> 6, l = tid & 63;
    const int wm = (w & 1) * 64, wn = (w >> 1) * 64;
    const int lm = l & 15, lg = l >> 4, hk = lg * 8;
    const int sr = tid >> 2, sc = (tid & 3) * 8;

    f32x4 acc[4][4];
#pragma unroll
    for (int a = 0; a < 4; ++a)
#pragma unroll
        for (int b = 0; b < 4; ++b) { acc[a][b][0]=0.f; acc[a][b][1]=0.f; acc[a][b][2]=0.f; acc[a][b][3]=0.f; }

    for (int ko = 0; ko < INF; ko += 32) {
        __syncthreads();
        u16x8 h, lo;
        cvt8_hilo(&X[(size_t)(m0+sr)*INF + ko + sc], &h, &lo);
        *(u16x8*)&Ah[sr][sc] = h;  *(u16x8*)&Al[sr][sc] = lo;
        cvt8_hilo(&X[(size_t)(m0+sr+64)*INF + ko + sc], &h, &lo);
        *(u16x8*)&Ah[sr+64][sc] = h;  *(u16x8*)&Al[sr+64][sc] = lo;
        *(u16x8*)&Bs[sr][sc]    = cvt8_hi(&Wih[(size_t)(n0+sr)*INF + ko + sc]);
        *(u16x8*)&Bs[sr+64][sc] = cvt8_hi(&Wih[(size_t)(n0+sr+64)*INF + ko + sc]);
        __syncthreads();
        frag16 afh[4], afl[4], bf[4];
#pragma unroll
        for (int i = 0; i < 4; ++i) afh[i] = *(const frag16*)&Ah[wm + i*16 + lm][hk];
#pragma unroll
        for (int i = 0; i < 4; ++i) afl[i] = *(const frag16*)&Al[wm + i*16 + lm][hk];
#pragma unroll
        for (int i = 0; i < 4; ++i) bf[i]  = *(const frag16*)&Bs[wn + i*16 + lm][hk];
#pragma unroll
        for (int a = 0; a < 4; ++a)
#pragma unroll
            for (int b = 0; b < 4; ++b) {
                acc[a][b] = __builtin_amdgcn_mfma_f32_16x16x32_bf16(afh[a], bf[b], acc[a][b], 0, 0, 0);
                acc[a][b] = __builtin_amdgcn_mfma_f32_16x16x32_bf16(afl[a], bf[b], acc[a][b], 0, 0, 0);
            }
    }

#pragma unroll
    for (int b = 0; b < 4; ++b) {
        const int n = n0 + wn + b*16 + lm;
        const float bias = bih[n] + bhh[n];
#pragma unroll
        for (int a = 0; a < 4; ++a)
#pragma unroll
            for (int q = 0; q < 4; ++q) {
                const int m = m0 + wm + a*16 + lg*4 + q;
                XP[(size_t)m * HID + n] = acc[a][b][q] + bias;
            }
    }
}

// ---------------- Phase 2: persistent scan ------------------------------------
// 256 blocks = 8 groups x 32 blocks. Group g owns batches [8g,8g+8); block r owns
// W_hh rows [32r, 32r+32) in LDS (bf16). Per step: flag-wait group, stage group's
// fp32 h to LDS, h (hi/lo bf16 split) @ W^T via MFMA, tanh in fp32, store,
// release fence + flag.
__global__ __launch_bounds__(256, 1)
void rnn_scan_kernel(const float* __restrict__ XP, const float* __restrict__ Whh,
                     float* __restrict__ H0, float* __restrict__ H1, int* flags)
{
    __shared__ ushort_t Ws[RPB][1032];        // 66,048 B ; stride 516 words
    __shared__ float    Hf[NB][1028];         // 32,896 B
    __shared__ float    Cred[4][2][16][16];   //  8,192 B

    const int tid = (int)threadIdx.x;
    const int w = tid >> 6, l = tid & 63;
    const int lm = l & 15, lg = l >> 4, hk = lg * 8;
    const int gid = (int)blockIdx.x / BPG;
    const int r   = (int)blockIdx.x % BPG;
    const int b0 = gid * NB;
    const int j0 = r * RPB;
    int* gflags = flags + gid * BPG;

    // Load this block's W_hh rows into LDS as bf16 (once).
    {
        const int rr = tid >> 3, seg = (tid & 7) * 128;
        const float* src = Whh + (size_t)(j0 + rr) * HID + seg;
#pragma unroll
        for (int i = 0; i < 16; ++i)
            *(u16x8*)&Ws[rr][seg + i*8] = cvt8_hi(&src[i*8]);
    }
    __syncthreads();

    for (int t = 0; t < SEQ; ++t) {
        float* hn       = (t & 1) ? H1 : H0;
        const float* hp = (t & 1) ? H0 : H1;

        // prefetch xp for the finish phase (independent of h)
        float xpv[4];
        if (w < 2) {
#pragma unroll
            for (int q = 0; q < 4; ++q) {
                const int m = lg * 4 + q;
                xpv[q] = 0.f;
                if (m < NB)
                    xpv[q] = XP[(size_t)((b0 + m) * SEQ + t) * HID + (j0 + w*16 + lm)];
            }
        }

        if (t > 0) {
            // wait until whole group finished step t-1
            if (w == 0) {
                for (;;) {
                    int v = t;
                    if (l < BPG)
                        v = __hip_atomic_load(&gflags[l], __ATOMIC_RELAXED, __HIP_MEMORY_SCOPE_AGENT);
                    if (__all(v >= t)) break;
                    __builtin_amdgcn_s_sleep(2);
                }
                __builtin_amdgcn_fence(__ATOMIC_ACQUIRE, "agent");
            }
            __syncthreads();
            // stage group's h_{t-1} (8 x 1024 fp32) into LDS
            {
                const int b = tid >> 5, c0 = (tid & 31) * 32;
                const float* src = hp + (size_t)(b0 + b) * HID + c0;
                float* dst = &Hf[b][c0];
#pragma unroll
                for (int i = 0; i < 8; ++i)
                    *(float4*)&dst[i*4] = *(const float4*)&src[i*4];
            }
            __syncthreads();

            // MFMA: wave w does K-quarter [256w, 256w+256), both 16-col tiles
            f32x4 a0, a1;
            a0[0]=0.f;a0[1]=0.f;a0[2]=0.f;a0[3]=0.f;
            a1[0]=0.f;a1[1]=0.f;a1[2]=0.f;a1[3]=0.f;
            const int kbase = w * 256;
#pragma unroll
            for (int kk = 0; kk < 256; kk += 32) {
                const int k0 = kbase + kk;
                frag16 ahi, alo;
#pragma unroll
                for (int j = 0; j < 8; ++j) { ahi[j] = 0; alo[j] = 0; }
                if (lm < NB) {
                    const float* hr = &Hf[lm][k0 + hk];
                    const float4 x0 = *(const float4*)hr;
                    const float4 x1 = *(const float4*)(hr + 4);
                    float xs[8] = {x0.x,x0.y,x0.z,x0.w,x1.x,x1.y,x1.z,x1.w};
#pragma unroll
                    for (int j = 0; j < 8; ++j) {
                        const ushort_t hi = f2b(xs[j]);
                        const float lo    = xs[j] - b2f(hi);
                        ahi[j] = (short)hi;
                        alo[j] = (short)f2b(lo);
                    }
                }
                const frag16 w0 = *(const frag16*)&Ws[lm][k0 + hk];
                const frag16 w1 = *(const frag16*)&Ws[16 + lm][k0 + hk];
                a0 = __builtin_amdgcn_mfma_f32_16x16x32_bf16(ahi, w0, a0, 0, 0, 0);
                a0 = __builtin_amdgcn_mfma_f32_16x16x32_bf16(alo, w0, a0, 0, 0, 0);
                a1 = __builtin_amdgcn_mfma_f32_16x16x32_bf16(ahi, w1, a1, 0, 0, 0);
                a1 = __builtin_amdgcn_mfma_f32_16x16x32_bf16(alo, w1, a1, 0, 0, 0);
            }
#pragma unroll
            for (int q = 0; q < 4; ++q) {
                Cred[w][0][lg*4 + q][lm] = a0[q];
                Cred[w][1][lg*4 + q][lm] = a1[q];
            }
            __syncthreads();
        }

        // finish: waves 0,1 own tiles 0,1 (16 cols each)
        if (w < 2) {
            const int jt = j0 + w*16 + lm;
#pragma unroll
            for (int q = 0; q < 4; ++q) {
                const int m = lg * 4 + q;
                if (m < NB) {
                    float s = 0.f;
                    if (t > 0)
                        s = Cred[0][w][m][lm] + Cred[1][w][m][lm]
                          + Cred[2][w][m][lm] + Cred[3][w][m][lm];
                    const float v = tanhf(s + xpv[q]);
                    hn[(size_t)(b0 + m) * HID + jt] = v;
                }
            }
        }
        __syncthreads();   // all waves' work for step t done before flag
        if (tid == 0) {
            __builtin_amdgcn_fence(__ATOMIC_RELEASE, "agent");
            __hip_atomic_store(&gflags[r], t + 1, __ATOMIC_RELAXED, __HIP_MEMORY_SCOPE_AGENT);
        }
    }
}

// ---------------- Phase 3: Out[b][n] = sum_k H[b,k]*Who[n,k] + bho[n] ----------
__global__ __launch_bounds__(256)
void outproj_kernel(const float* __restrict__ H, const float* __restrict__ Who,
                    const float* __restrict__ bho, float* __restrict__ Out)
{
    const int tid = (int)threadIdx.x;
    const int w = tid >> 6, l = tid & 63;
    const int lm = l & 15, lg = l >> 4, hk = lg * 8;
    const int n0 = (int)blockIdx.x * 64;

    f32x4 acc[4];
#pragma unroll
    for (int i = 0; i < 4; ++i) { acc[i][0]=0.f; acc[i][1]=0.f; acc[i][2]=0.f; acc[i][3]=0.f; }

    for (int k0 = 0; k0 < HID; k0 += 32) {
        const u16x8 av = cvt8_hi(H + (size_t)(w*16 + lm) * HID + k0 + hk);
        const frag16 a = (frag16)av;
#pragma unroll
        for (int bi = 0; bi < 4; ++bi) {
            const u16x8 bv = cvt8_hi(&Who[(size_t)(n0 + bi*16 + lm) * HID + k0 + hk]);
            acc[bi] = __builtin_amdgcn_mfma_f32_16x16x32_bf16(a, (frag16)bv, acc[bi], 0, 0, 0);
        }
    }
#pragma unroll
    for (int bi = 0; bi < 4; ++bi) {
        const int n = n0 + bi*16 + lm;
        const float bias = bho[n];
#pragma unroll
        for (int q = 0; q < 4; ++q) {
            const int b = w*16 + lg*4 + q;
            Out[(size_t)b * OUTF + n] = acc[bi][q] + bias;
        }
    }
}

// ---------------- launcher -----------------------------------------------------
extern "C" void kernel_launch(void* const* d_in, const int* in_sizes, int n_in,
                              void* d_out, int out_size, void* d_ws, size_t ws_size,
                              hipStream_t stream)
{
    const float* X   = (const float*)d_in[0];
    const float* Wih = (const float*)d_in[1];
    const float* bih = (const float*)d_in[2];
    const float* Whh = (const float*)d_in[3];
    const float* bhh = (const float*)d_in[4];
    const float* Who = (const float*)d_in[5];
    const float* bho = (const float*)d_in[6];
    float* Out = (float*)d_out;

    char* ws = (char*)d_ws;
    float* XP = (float*)ws;                                   // 32768*1024*4 = 128 MiB
    float* H0 = (float*)(ws + (size_t)32768 * 1024 * 4);      // 256 KiB
    float* H1 = H0 + 64 * HID;                                // 256 KiB
    int* flags = (int*)(H1 + 64 * HID);                       // 1 KiB

    hipMemsetAsync(flags, 0, GROUPS * BPG * sizeof(int), stream);

    xproj_kernel<<<dim3(256, 8), dim3(256), 0, stream>>>(X, Wih, bih, bhh, XP);

    // 256 blocks, 1/CU (107 KiB LDS) -> all co-resident on 256 CUs.
    rnn_scan_kernel<<<dim3(GROUPS * BPG), dim3(256), 0, stream>>>(XP, Whh, H0, H1, flags);

    outproj_kernel<<<dim3(OUTF / 64), dim3(256), 0, stream>>>(H1, Who, bho, Out);
}

// Round 3
// 4096.132 us; speedup vs baseline: 1.3317x; 1.3317x over previous
//
#include <hip/hip_runtime.h>
#include <cstdint>
#include <cstddef>

typedef unsigned short ushort_t;
typedef __attribute__((ext_vector_type(8))) short frag16;
typedef __attribute__((ext_vector_type(8))) unsigned short u16x8;
typedef __attribute__((ext_vector_type(4))) float f32x4;

#define SEQ   512
#define INF   512
#define HID   1024
#define OUTF  512
#define GROUPS 8
#define BPG    32   // blocks per group
#define NB     8    // batches per group
#define RPB    32   // W_hh rows (output cols) per block

__device__ __forceinline__ float b2f(ushort_t u) {
    union { unsigned int i; float f; } v; v.i = ((unsigned int)u) << 16; return v.f;
}
__device__ __forceinline__ ushort_t f2b(float f) {  // RNE fp32->bf16
    unsigned int u = __float_as_uint(f);
    unsigned int r = (u + 0x7fffu + ((u >> 16) & 1u)) >> 16;
    return (ushort_t)r;
}
__device__ __forceinline__ float fast_tanh(float s) {
    // tanh(s) = 1 - 2/(e^{2s}+1); exp->inf / ->0 degrade gracefully to +-1
    const float e = __expf(2.0f * s);
    return 1.0f - 2.0f * __builtin_amdgcn_rcpf(e + 1.0f);
}

// convert 8 contiguous fp32 -> bf16 hi (+ optional lo residual)
__device__ __forceinline__ void cvt8_hilo(const float* __restrict__ src, u16x8* hi, u16x8* lo) {
    const float4 x0 = *(const float4*)src;
    const float4 x1 = *(const float4*)(src + 4);
    float xs[8] = {x0.x,x0.y,x0.z,x0.w,x1.x,x1.y,x1.z,x1.w};
    u16x8 h, l;
#pragma unroll
    for (int j = 0; j < 8; ++j) {
        const ushort_t hb = f2b(xs[j]);
        h[j] = hb;
        l[j] = f2b(xs[j] - b2f(hb));
    }
    *hi = h; if (lo) *lo = l;
}
__device__ __forceinline__ u16x8 cvt8_hi(const float* __restrict__ src) {
    const float4 x0 = *(const float4*)src;
    const float4 x1 = *(const float4*)(src + 4);
    float xs[8] = {x0.x,x0.y,x0.z,x0.w,x1.x,x1.y,x1.z,x1.w};
    u16x8 h;
#pragma unroll
    for (int j = 0; j < 8; ++j) h[j] = f2b(xs[j]);
    return h;
}

// ---------------- Phase 1: XP[m][n] = sum_k X[m,k]*Wih[n,k] + bih[n] + bhh[n] ----
__global__ __launch_bounds__(256, 2)
void xproj_kernel(const float* __restrict__ X, const float* __restrict__ Wih,
                  const float* __restrict__ bih, const float* __restrict__ bhh,
                  float* __restrict__ XP)
{
    __shared__ ushort_t Ah[128][40];
    __shared__ ushort_t Al[128][40];
    __shared__ ushort_t Bs[128][40];
    const int tid = (int)threadIdx.x;
    const int m0 = (int)blockIdx.x * 128;
    const int n0 = (int)blockIdx.y * 128;
    const int w  = tid >> 6, l = tid & 63;
    const int wm = (w & 1) * 64, wn = (w >> 1) * 64;
    const int lm = l & 15, lg = l >> 4, hk = lg * 8;
    const int sr = tid >> 2, sc = (tid & 3) * 8;

    f32x4 acc[4][4];
#pragma unroll
    for (int a = 0; a < 4; ++a)
#pragma unroll
        for (int b = 0; b < 4; ++b) { acc[a][b][0]=0.f; acc[a][b][1]=0.f; acc[a][b][2]=0.f; acc[a][b][3]=0.f; }

    for (int ko = 0; ko < INF; ko += 32) {
        __syncthreads();
        u16x8 h, lo;
        cvt8_hilo(&X[(size_t)(m0+sr)*INF + ko + sc], &h, &lo);
        *(u16x8*)&Ah[sr][sc] = h;  *(u16x8*)&Al[sr][sc] = lo;
        cvt8_hilo(&X[(size_t)(m0+sr+64)*INF + ko + sc], &h, &lo);
        *(u16x8*)&Ah[sr+64][sc] = h;  *(u16x8*)&Al[sr+64][sc] = lo;
        *(u16x8*)&Bs[sr][sc]    = cvt8_hi(&Wih[(size_t)(n0+sr)*INF + ko + sc]);
        *(u16x8*)&Bs[sr+64][sc] = cvt8_hi(&Wih[(size_t)(n0+sr+64)*INF + ko + sc]);
        __syncthreads();
        frag16 afh[4], afl[4], bf[4];
#pragma unroll
        for (int i = 0; i < 4; ++i) afh[i] = *(const frag16*)&Ah[wm + i*16 + lm][hk];
#pragma unroll
        for (int i = 0; i < 4; ++i) afl[i] = *(const frag16*)&Al[wm + i*16 + lm][hk];
#pragma unroll
        for (int i = 0; i < 4; ++i) bf[i]  = *(const frag16*)&Bs[wn + i*16 + lm][hk];
#pragma unroll
        for (int a = 0; a < 4; ++a)
#pragma unroll
            for (int b = 0; b < 4; ++b) {
                acc[a][b] = __builtin_amdgcn_mfma_f32_16x16x32_bf16(afh[a], bf[b], acc[a][b], 0, 0, 0);
                acc[a][b] = __builtin_amdgcn_mfma_f32_16x16x32_bf16(afl[a], bf[b], acc[a][b], 0, 0, 0);
            }
    }

#pragma unroll
    for (int b = 0; b < 4; ++b) {
        const int n = n0 + wn + b*16 + lm;
        const float bias = bih[n] + bhh[n];
#pragma unroll
        for (int a = 0; a < 4; ++a)
#pragma unroll
            for (int q = 0; q < 4; ++q) {
                const int m = m0 + wm + a*16 + lg*4 + q;
                XP[(size_t)m * HID + n] = acc[a][b][q] + bias;
            }
    }
}

// ---------------- Phase 2: persistent scan, fence-free atomic exchange ----------
// h carried as u32 = bf16_hi | bf16_lo<<16 (fp32-equivalent). Exchange via
// device-scope relaxed atomics (sc1 coherence-point ops): NO buffer_inv / wbl2.
// Per-wave flags: wave w of block r releases gwf[r*2+w] after vmcnt drain.
__global__ __launch_bounds__(256, 1)
void rnn_scan_kernel(const float* __restrict__ XP, const float* __restrict__ Whh,
                     unsigned int* __restrict__ Hp0, unsigned int* __restrict__ Hp1,
                     int* flags)
{
    __shared__ ushort_t     Ws[RPB][1032];     // 66,048 B ; 516 words/row (==4 mod 32)
    __shared__ unsigned int Hst[NB][1028];     // 32,896 B ; 1028 words/row (==4 mod 32)
    __shared__ float        Cred[4][2][16][16];//  8,192 B   -> 107 KB total, 1 block/CU

    const int tid = (int)threadIdx.x;
    const int w = tid >> 6, l = tid & 63;
    const int lm = l & 15, lg = l >> 4;
    const int gid = (int)blockIdx.x >> 5;
    const int r   = (int)blockIdx.x & 31;
    const int b0 = gid * NB;
    const int j0 = r * RPB;
    int* gwf = flags + gid * 64;               // 64 wave-flags per group

    // Load this block's W_hh rows into LDS as bf16 (once).
    {
        const int rr = tid >> 3, seg = (tid & 7) * 128;
        const float* src = Whh + (size_t)(j0 + rr) * HID + seg;
#pragma unroll
        for (int i = 0; i < 16; ++i)
            *(u16x8*)&Ws[rr][seg + i*8] = cvt8_hi(&src[i*8]);
    }
    __syncthreads();

    for (int t = 0; t < SEQ; ++t) {
        unsigned int* hn       = (t & 1) ? Hp1 : Hp0;
        const unsigned int* hp = (t & 1) ? Hp0 : Hp1;

        // prefetch xp (plain cached loads; XP stays hot in L1/L2 now)
        float xpv[4];
        if (w < 2) {
#pragma unroll
            for (int q = 0; q < 4; ++q) {
                const int m = lg * 4 + q;
                xpv[q] = 0.f;
                if (m < NB)
                    xpv[q] = XP[(size_t)((b0 + m) * SEQ + t) * HID + (j0 + w*16 + lm)];
            }
        }

        if (t > 0) {
            // each wave independently polls all 64 wave-flags of its group
            for (;;) {
                int v = __hip_atomic_load(&gwf[l], __ATOMIC_RELAXED, __HIP_MEMORY_SCOPE_AGENT);
                if (__all(v >= t)) break;
                __builtin_amdgcn_s_sleep(1);
            }
            __builtin_amdgcn_fence(__ATOMIC_ACQUIRE, "workgroup");  // compiler barrier, no cache inv

            // cooperative stage: 256 lanes pull 8x1024 packed u32 (32 KB) via b64 CP loads
            {
                const int sb = tid >> 5, sc2 = tid & 31;
                const unsigned long long* src =
                    (const unsigned long long*)(hp + (size_t)(b0 + sb) * HID);
                unsigned long long vals[16];
#pragma unroll
                for (int i = 0; i < 16; ++i)
                    vals[i] = __hip_atomic_load(&src[sc2 + i*32], __ATOMIC_RELAXED,
                                                __HIP_MEMORY_SCOPE_AGENT);
#pragma unroll
                for (int i = 0; i < 16; ++i)
                    *(unsigned long long*)&Hst[sb][2*sc2 + i*64] = vals[i];
            }
            __syncthreads();

            // MFMA: wave w does K-quarter [256w,256w+256), both 16-col tiles
            f32x4 a0, a1;
            a0[0]=0.f;a0[1]=0.f;a0[2]=0.f;a0[3]=0.f;
            a1[0]=0.f;a1[1]=0.f;a1[2]=0.f;a1[3]=0.f;
            const int kbase = w * 256;
#pragma unroll
            for (int kk = 0; kk < 256; kk += 32) {
                const int k0 = kbase + kk;
                frag16 ahi, alo;
#pragma unroll
                for (int j = 0; j < 8; ++j) { ahi[j] = 0; alo[j] = 0; }
                if (lm < NB) {
                    const unsigned int* hr = &Hst[lm][k0 + lg*8];
                    const uint4 d0 = *(const uint4*)hr;
                    const uint4 d1 = *(const uint4*)(hr + 4);
                    unsigned int dd[8] = {d0.x,d0.y,d0.z,d0.w,d1.x,d1.y,d1.z,d1.w};
#pragma unroll
                    for (int j = 0; j < 8; ++j) {
                        ahi[j] = (short)(dd[j] & 0xffffu);
                        alo[j] = (short)(dd[j] >> 16);
                    }
                }
                const frag16 w0 = *(const frag16*)&Ws[lm][k0 + lg*8];
                const frag16 w1 = *(const frag16*)&Ws[16 + lm][k0 + lg*8];
                a0 = __builtin_amdgcn_mfma_f32_16x16x32_bf16(ahi, w0, a0, 0, 0, 0);
                a0 = __builtin_amdgcn_mfma_f32_16x16x32_bf16(alo, w0, a0, 0, 0, 0);
                a1 = __builtin_amdgcn_mfma_f32_16x16x32_bf16(ahi, w1, a1, 0, 0, 0);
                a1 = __builtin_amdgcn_mfma_f32_16x16x32_bf16(alo, w1, a1, 0, 0, 0);
            }
#pragma unroll
            for (int q = 0; q < 4; ++q) {
                Cred[w][0][lg*4 + q][lm] = a0[q];
                Cred[w][1][lg*4 + q][lm] = a1[q];
            }
            __syncthreads();
        }

        // finish: waves 0,1 own the two 16-col tiles
        if (w < 2) {
            const int jt = j0 + w*16 + lm;
#pragma unroll
            for (int q = 0; q < 4; ++q) {
                const int m = lg * 4 + q;
                if (m < NB) {
                    float s = 0.f;
                    if (t > 0)
                        s = Cred[0][w][m][lm] + Cred[1][w][m][lm]
                          + Cred[2][w][m][lm] + Cred[3][w][m][lm];
                    const float v = fast_tanh(s + xpv[q]);
                    const ushort_t hi = f2b(v);
                    const ushort_t lo = f2b(v - b2f(hi));
                    const unsigned int pk = (unsigned int)hi | ((unsigned int)lo << 16);
                    __hip_atomic_store(&hn[(size_t)(b0 + m) * HID + jt], pk,
                                       __ATOMIC_RELAXED, __HIP_MEMORY_SCOPE_AGENT);
                }
            }
            // drain this wave's CP stores (s_waitcnt vmcnt(0), no cache ops), then flag
            __builtin_amdgcn_fence(__ATOMIC_RELEASE, "workgroup");
            if (l == 0)
                __hip_atomic_store(&gwf[r*2 + w], t + 1,
                                   __ATOMIC_RELAXED, __HIP_MEMORY_SCOPE_AGENT);
        }
    }
}

// ---------------- Phase 3: Out[b][n] = sum_k H[b,k]*Who[n,k] + bho[n] ----------
// H arrives packed (hi|lo<<16); use hi and lo as two A-operands (fp32-equivalent).
__global__ __launch_bounds__(256)
void outproj_kernel(const unsigned int* __restrict__ Hp, const float* __restrict__ Who,
                    const float* __restrict__ bho, float* __restrict__ Out)
{
    const int tid = (int)threadIdx.x;
    const int w = tid >> 6, l = tid & 63;
    const int lm = l & 15, lg = l >> 4, hk = lg * 8;
    const int n0 = (int)blockIdx.x * 64;

    f32x4 acc[4];
#pragma unroll
    for (int i = 0; i < 4; ++i) { acc[i][0]=0.f; acc[i][1]=0.f; acc[i][2]=0.f; acc[i][3]=0.f; }

    for (int k0 = 0; k0 < HID; k0 += 32) {
        const unsigned int* hr = Hp + (size_t)(w*16 + lm) * HID + k0 + hk;
        const uint4 d0 = *(const uint4*)hr;
        const uint4 d1 = *(const uint4*)(hr + 4);
        unsigned int dd[8] = {d0.x,d0.y,d0.z,d0.w,d1.x,d1.y,d1.z,d1.w};
        frag16 ahi, alo;
#pragma unroll
        for (int j = 0; j < 8; ++j) {
            ahi[j] = (short)(dd[j] & 0xffffu);
            alo[j] = (short)(dd[j] >> 16);
        }
#pragma unroll
        for (int bi = 0; bi < 4; ++bi) {
            const u16x8 bv = cvt8_hi(&Who[(size_t)(n0 + bi*16 + lm) * HID + k0 + hk]);
            acc[bi] = __builtin_amdgcn_mfma_f32_16x16x32_bf16(ahi, (frag16)bv, acc[bi], 0, 0, 0);
            acc[bi] = __builtin_amdgcn_mfma_f32_16x16x32_bf16(alo, (frag16)bv, acc[bi], 0, 0, 0);
        }
    }
#pragma unroll
    for (int bi = 0; bi < 4; ++bi) {
        const int n = n0 + bi*16 + lm;
        const float bias = bho[n];
#pragma unroll
        for (int q = 0; q < 4; ++q) {
            const int b = w*16 + lg*4 + q;
            Out[(size_t)b * OUTF + n] = acc[bi][q] + bias;
        }
    }
}

// ---------------- launcher -----------------------------------------------------
extern "C" void kernel_launch(void* const* d_in, const int* in_sizes, int n_in,
                              void* d_out, int out_size, void* d_ws, size_t ws_size,
                              hipStream_t stream)
{
    const float* X   = (const float*)d_in[0];
    const float* Wih = (const float*)d_in[1];
    const float* bih = (const float*)d_in[2];
    const float* Whh = (const float*)d_in[3];
    const float* bhh = (const float*)d_in[4];
    const float* Who = (const float*)d_in[5];
    const float* bho = (const float*)d_in[6];
    float* Out = (float*)d_out;

    char* ws = (char*)d_ws;
    float* XP = (float*)ws;                                        // 128 MiB
    unsigned int* Hp0 = (unsigned int*)(ws + (size_t)32768 * 1024 * 4);  // 256 KiB
    unsigned int* Hp1 = Hp0 + 64 * HID;                            // 256 KiB
    int* flags = (int*)(Hp1 + 64 * HID);                           // 2 KiB

    hipMemsetAsync(flags, 0, GROUPS * 64 * sizeof(int), stream);

    xproj_kernel<<<dim3(256, 8), dim3(256), 0, stream>>>(X, Wih, bih, bhh, XP);

    rnn_scan_kernel<<<dim3(GROUPS * BPG), dim3(256), 0, stream>>>(XP, Whh, Hp0, Hp1, flags);

    // SEQ=512 is even -> final h lives in Hp1 (t=511 wrote (511&1)?Hp1:Hp0 = Hp1)
    outproj_kernel<<<dim3(OUTF / 64), dim3(256), 0, stream>>>(Hp1, Who, bho, Out);
}

// Round 6
// 2128.537 us; speedup vs baseline: 2.5627x; 1.9244x over previous
//
#include <hip/hip_runtime.h>
#include <cstdint>
#include <cstddef>

typedef unsigned short ushort_t;
typedef unsigned int uint_t;
typedef unsigned long long u64_t;
typedef __attribute__((ext_vector_type(8))) short frag16;
typedef __attribute__((ext_vector_type(8))) unsigned short u16x8;
typedef __attribute__((ext_vector_type(4))) float f32x4;

#define SEQ   512
#define INF   512
#define HID   1024
#define OUTF  512
#define GROUPS 16
#define BPG    16   // blocks per group
#define NB     4    // batches per group
#define RPB    64   // W_hh rows (output cols) per block
#define SPIN_LIMIT (1 << 18)

__device__ __forceinline__ float b2f(ushort_t u) {
    union { unsigned int i; float f; } v; v.i = ((unsigned int)u) << 16; return v.f;
}
__device__ __forceinline__ ushort_t f2b(float f) {  // RNE fp32->bf16
    unsigned int u = __float_as_uint(f);
    unsigned int r = (u + 0x7fffu + ((u >> 16) & 1u)) >> 16;
    return (ushort_t)r;
}
__device__ __forceinline__ float fast_tanh(float s) {
    const float e = __expf(2.0f * s);
    return 1.0f - 2.0f * __builtin_amdgcn_rcpf(e + 1.0f);
}

__device__ __forceinline__ void cvt8_hilo(const float* __restrict__ src, u16x8* hi, u16x8* lo) {
    const float4 x0 = *(const float4*)src;
    const float4 x1 = *(const float4*)(src + 4);
    float xs[8] = {x0.x,x0.y,x0.z,x0.w,x1.x,x1.y,x1.z,x1.w};
    u16x8 h, l;
#pragma unroll
    for (int j = 0; j < 8; ++j) {
        const ushort_t hb = f2b(xs[j]);
        h[j] = hb;
        l[j] = f2b(xs[j] - b2f(hb));
    }
    *hi = h; if (lo) *lo = l;
}
__device__ __forceinline__ u16x8 cvt8_hi(const float* __restrict__ src) {
    const float4 x0 = *(const float4*)src;
    const float4 x1 = *(const float4*)(src + 4);
    float xs[8] = {x0.x,x0.y,x0.z,x0.w,x1.x,x1.y,x1.z,x1.w};
    u16x8 h;
#pragma unroll
    for (int j = 0; j < 8; ++j) h[j] = f2b(xs[j]);
    return h;
}

// ---------------- Phase 1: XP[m][n] = sum_k X[m,k]*Wih[n,k] + bih[n] + bhh[n] ----
__global__ __launch_bounds__(256, 2)
void xproj_kernel(const float* __restrict__ X, const float* __restrict__ Wih,
                  const float* __restrict__ bih, const float* __restrict__ bhh,
                  float* __restrict__ XP)
{
    __shared__ ushort_t Ah[128][40];
    __shared__ ushort_t Al[128][40];
    __shared__ ushort_t Bs[128][40];
    const int tid = (int)threadIdx.x;
    const int m0 = (int)blockIdx.x * 128;
    const int n0 = (int)blockIdx.y * 128;
    const int w  = tid >> 6, l = tid & 63;
    const int wm = (w & 1) * 64, wn = (w >> 1) * 64;
    const int lm = l & 15, lg = l >> 4, hk = lg * 8;
    const int sr = tid >> 2, sc = (tid & 3) * 8;

    f32x4 acc[4][4];
#pragma unroll
    for (int a = 0; a < 4; ++a)
#pragma unroll
        for (int b = 0; b < 4; ++b) { acc[a][b][0]=0.f; acc[a][b][1]=0.f; acc[a][b][2]=0.f; acc[a][b][3]=0.f; }

    for (int ko = 0; ko < INF; ko += 32) {
        __syncthreads();
        u16x8 h, lo;
        cvt8_hilo(&X[(size_t)(m0+sr)*INF + ko + sc], &h, &lo);
        *(u16x8*)&Ah[sr][sc] = h;  *(u16x8*)&Al[sr][sc] = lo;
        cvt8_hilo(&X[(size_t)(m0+sr+64)*INF + ko + sc], &h, &lo);
        *(u16x8*)&Ah[sr+64][sc] = h;  *(u16x8*)&Al[sr+64][sc] = lo;
        *(u16x8*)&Bs[sr][sc]    = cvt8_hi(&Wih[(size_t)(n0+sr)*INF + ko + sc]);
        *(u16x8*)&Bs[sr+64][sc] = cvt8_hi(&Wih[(size_t)(n0+sr+64)*INF + ko + sc]);
        __syncthreads();
        frag16 afh[4], afl[4], bf[4];
#pragma unroll
        for (int i = 0; i < 4; ++i) afh[i] = *(const frag16*)&Ah[wm + i*16 + lm][hk];
#pragma unroll
        for (int i = 0; i < 4; ++i) afl[i] = *(const frag16*)&Al[wm + i*16 + lm][hk];
#pragma unroll
        for (int i = 0; i < 4; ++i) bf[i]  = *(const frag16*)&Bs[wn + i*16 + lm][hk];
#pragma unroll
        for (int a = 0; a < 4; ++a)
#pragma unroll
            for (int b = 0; b < 4; ++b) {
                acc[a][b] = __builtin_amdgcn_mfma_f32_16x16x32_bf16(afh[a], bf[b], acc[a][b], 0, 0, 0);
                acc[a][b] = __builtin_amdgcn_mfma_f32_16x16x32_bf16(afl[a], bf[b], acc[a][b], 0, 0, 0);
            }
    }

#pragma unroll
    for (int b = 0; b < 4; ++b) {
        const int n = n0 + wn + b*16 + lm;
        const float bias = bih[n] + bhh[n];
#pragma unroll
        for (int a = 0; a < 4; ++a)
#pragma unroll
            for (int q = 0; q < 4; ++q) {
                const int m = m0 + wm + a*16 + lg*4 + q;
                XP[(size_t)m * HID + n] = acc[a][b][q] + bias;
            }
    }
}

// ---------------- Phase 2: persistent scan, tagged-data exchange ---------------
// 256 blocks = 16 groups x 16 blocks; group g owns batches [4g,4g+4); block r
// owns 64 cols in LDS (132 KB bf16 W). h travels as one 8-byte agent-scope
// relaxed atomic word: (packed_bf16hi|lo << 32) | (t+1). Single-copy atomicity
// makes the data its own ready flag: no fences, no vmcnt release, no flag hops.
// Ping-pong buffers (R=2) proven safe: producer enters step t+1 only after
// gathering all tags t, which implies all group-mates finished reading tags t-1.
__global__ __launch_bounds__(256, 1)
void rnn_scan_kernel(const float* __restrict__ XP, const float* __restrict__ Whh,
                     u64_t* __restrict__ Hbuf)
{
    __shared__ ushort_t Ws[RPB][1032];        // 132,096 B
    __shared__ uint_t   Hst[NB][1028];        //  16,448 B (packed hi|lo)
    __shared__ float    Cred[4][4][4][16];    //   4,096 B -> 152.6 KB, 1 block/CU

    const int tid = (int)threadIdx.x;
    const int w = tid >> 6, l = tid & 63;     // wave, lane
    const int lm = l & 15, lg = l >> 4;
    const int gid = (int)blockIdx.x >> 4;     // group = blockIdx/16
    const int r   = (int)blockIdx.x & 15;
    const int b0 = gid * NB;
    const int j0 = r * RPB;

    // Load this block's 64 W_hh rows into LDS as bf16 (once).
    {
        const int rr = tid >> 2, cq = (tid & 3) * 256;
        const float* src = Whh + (size_t)(j0 + rr) * HID + cq;
#pragma unroll
        for (int i = 0; i < 32; ++i)
            *(u16x8*)&Ws[rr][cq + i*8] = cvt8_hi(&src[i*8]);
    }
    __syncthreads();

    for (int t = 0; t < SEQ; ++t) {
        // xp prefetch for the finish phase (lanes 0..15 of each wave)
        float xpv[4];
        if (l < 16) {
#pragma unroll
            for (int q = 0; q < 4; ++q)
                xpv[q] = XP[(size_t)((b0 + q) * SEQ + t) * HID + (j0 + w*16 + l)];
        }

        if (t > 0) {
            // ---- tagged gather: wave w pulls row (b0+w), cols l + 64j ----
            {
                const u64_t* rowp = Hbuf + ((size_t)((t - 1) & 1) * 64 + b0 + w) * 1024 + l;
                const uint_t want = (uint_t)t;     // tag written at step t-1
                u64_t v[16];
#pragma unroll
                for (int j = 0; j < 16; ++j)
                    v[j] = __hip_atomic_load(&rowp[j*64], __ATOMIC_RELAXED,
                                             __HIP_MEMORY_SCOPE_AGENT);
                int spin = 0;
                for (;;) {
                    int bad = 0;
#pragma unroll
                    for (int j = 0; j < 16; ++j) bad |= ((uint_t)v[j] != want);
                    if (!__any(bad)) break;
                    if (++spin > SPIN_LIMIT) break;   // hang-proof: finite-wrong
                    __builtin_amdgcn_s_sleep(1);
#pragma unroll
                    for (int j = 0; j < 16; ++j)
                        if ((uint_t)v[j] != want)
                            v[j] = __hip_atomic_load(&rowp[j*64], __ATOMIC_RELAXED,
                                                     __HIP_MEMORY_SCOPE_AGENT);
                }
#pragma unroll
                for (int j = 0; j < 16; ++j)
                    Hst[w][l + 64*j] = (uint_t)(v[j] >> 32);
            }
            __syncthreads();

            // ---- MFMA: wave w does K-quarter [256w,256w+256), 4 col-tiles ----
            f32x4 acc[4];
#pragma unroll
            for (int i = 0; i < 4; ++i) { acc[i][0]=0.f; acc[i][1]=0.f; acc[i][2]=0.f; acc[i][3]=0.f; }
            const int kbase = w * 256;
#pragma unroll
            for (int kk = 0; kk < 256; kk += 32) {
                const int k0 = kbase + kk;
                frag16 ahi, alo;
#pragma unroll
                for (int j = 0; j < 8; ++j) { ahi[j] = 0; alo[j] = 0; }
                if (lm < NB) {
                    const uint_t* hr = &Hst[lm][k0 + lg*8];
                    const uint4 d0 = *(const uint4*)hr;
                    const uint4 d1 = *(const uint4*)(hr + 4);
                    uint_t dd[8] = {d0.x,d0.y,d0.z,d0.w,d1.x,d1.y,d1.z,d1.w};
#pragma unroll
                    for (int j = 0; j < 8; ++j) {
                        ahi[j] = (short)(dd[j] & 0xffffu);
                        alo[j] = (short)(dd[j] >> 16);
                    }
                }
#pragma unroll
                for (int tl = 0; tl < 4; ++tl) {
                    const frag16 wf = *(const frag16*)&Ws[tl*16 + lm][k0 + lg*8];
                    acc[tl] = __builtin_amdgcn_mfma_f32_16x16x32_bf16(ahi, wf, acc[tl], 0, 0, 0);
                    acc[tl] = __builtin_amdgcn_mfma_f32_16x16x32_bf16(alo, wf, acc[tl], 0, 0, 0);
                }
            }
            if (lg == 0) {   // C rows 0..3 = the 4 real batches
#pragma unroll
                for (int tl = 0; tl < 4; ++tl)
#pragma unroll
                    for (int q = 0; q < 4; ++q)
                        Cred[w][tl][q][lm] = acc[tl][q];
            }
            __syncthreads();
        }

        // ---- finish: wave w owns cols [j0+16w, +16); lanes 0..15 active ----
        if (l < 16) {
            const int jt = j0 + w*16 + l;
            u64_t* outp = Hbuf + ((size_t)(t & 1) * 64 + b0) * 1024 + jt;
#pragma unroll
            for (int q = 0; q < 4; ++q) {
                float s = 0.f;
                if (t > 0)
                    s = Cred[0][w][q][l] + Cred[1][w][q][l]
                      + Cred[2][w][q][l] + Cred[3][w][q][l];
                const float v = fast_tanh(s + xpv[q]);
                const ushort_t hi = f2b(v);
                const ushort_t lo = f2b(v - b2f(hi));
                const u64_t pk = ((u64_t)((uint_t)hi | ((uint_t)lo << 16)) << 32)
                               | (u64_t)(uint_t)(t + 1);   // tag t+1, never 0
                __hip_atomic_store(&outp[(size_t)q * 1024], pk,
                                   __ATOMIC_RELAXED, __HIP_MEMORY_SCOPE_AGENT);
            }
        }
        // no barrier needed here: next-step Hst writes are gated by the
        // post-staging __syncthreads, and gather self-syncs on tags.
    }
}

// ---------------- Phase 3: Out[b][n] = sum_k H[b,k]*Who[n,k] + bho[n] ----------
// H arrives as tagged u64 (data in high dword, packed hi|lo<<16).
__global__ __launch_bounds__(256)
void outproj_kernel(const u64_t* __restrict__ Hp, const float* __restrict__ Who,
                    const float* __restrict__ bho, float* __restrict__ Out)
{
    const int tid = (int)threadIdx.x;
    const int w = tid >> 6, l = tid & 63;
    const int lm = l & 15, lg = l >> 4, hk = lg * 8;
    const int n0 = (int)blockIdx.x * 64;

    f32x4 acc[4];
#pragma unroll
    for (int i = 0; i < 4; ++i) { acc[i][0]=0.f; acc[i][1]=0.f; acc[i][2]=0.f; acc[i][3]=0.f; }

    for (int k0 = 0; k0 < HID; k0 += 32) {
        const u64_t* hr = Hp + (size_t)(w*16 + lm) * HID + k0 + hk;
        frag16 ahi, alo;
#pragma unroll
        for (int j = 0; j < 8; ++j) {
            const uint_t d = (uint_t)(hr[j] >> 32);
            ahi[j] = (short)(d & 0xffffu);
            alo[j] = (short)(d >> 16);
        }
#pragma unroll
        for (int bi = 0; bi < 4; ++bi) {
            const u16x8 bv = cvt8_hi(&Who[(size_t)(n0 + bi*16 + lm) * HID + k0 + hk]);
            acc[bi] = __builtin_amdgcn_mfma_f32_16x16x32_bf16(ahi, (frag16)bv, acc[bi], 0, 0, 0);
            acc[bi] = __builtin_amdgcn_mfma_f32_16x16x32_bf16(alo, (frag16)bv, acc[bi], 0, 0, 0);
        }
    }
#pragma unroll
    for (int bi = 0; bi < 4; ++bi) {
        const int n = n0 + bi*16 + lm;
        const float bias = bho[n];
#pragma unroll
        for (int q = 0; q < 4; ++q) {
            const int b = w*16 + lg*4 + q;
            Out[(size_t)b * OUTF + n] = acc[bi][q] + bias;
        }
    }
}

// ---------------- launcher -----------------------------------------------------
extern "C" void kernel_launch(void* const* d_in, const int* in_sizes, int n_in,
                              void* d_out, int out_size, void* d_ws, size_t ws_size,
                              hipStream_t stream)
{
    const float* X   = (const float*)d_in[0];
    const float* Wih = (const float*)d_in[1];
    const float* bih = (const float*)d_in[2];
    const float* Whh = (const float*)d_in[3];
    const float* bhh = (const float*)d_in[4];
    const float* Who = (const float*)d_in[5];
    const float* bho = (const float*)d_in[6];
    float* Out = (float*)d_out;

    char* ws = (char*)d_ws;
    float* XP = (float*)ws;                                        // 128 MiB
    u64_t* Hbuf = (u64_t*)(ws + (size_t)32768 * 1024 * 4);         // 2*64*1024*8 = 1 MiB
    // No memset needed: tags are t+1 (1..512); 0xAA-poison and zeros never match.

    xproj_kernel<<<dim3(256, 8), dim3(256), 0, stream>>>(X, Wih, bih, bhh, XP);

    rnn_scan_kernel<<<dim3(GROUPS * BPG), dim3(256), 0, stream>>>(XP, Whh, Hbuf);

    // SEQ=512 -> final step t=511 wrote buffer (511 & 1) = 1
    outproj_kernel<<<dim3(OUTF / 64), dim3(256), 0, stream>>>(Hbuf + (size_t)64 * 1024,
                                                              Who, bho, Out);
}